// Round 1
// baseline (115.397 us; speedup 1.0000x reference)
//
#include <hip/hip_runtime.h>
#include <math.h>

// HyperConnection collapses per-token to: out[d] = s_ho * h_o[d] + s_h * h[d]
//   s_h  = R*a_scale*sum_{c=1..4} tanh(rms * dot(h*w, fa[:,c])) + sum_{r,c>=1} sa[r,c]
//   s_ho = R*b_scale*tanh(rms * dot(h*w, fb)) + sum(sb)
//   rms  = rsqrt(mean(h^2)+eps)   (uniform per token -> hoist out of the dots)
// One 256-thread block per token (row of D=2048); 8 elems/thread in registers.

constexpr int D    = 2048;
constexpr int RATE = 4;
constexpr float EPS = 1e-5f;

__global__ __launch_bounds__(256) void hyperconn_kernel(
    const float* __restrict__ h,
    const float* __restrict__ h_o,
    const float* __restrict__ sa,    // [4][5]
    const float* __restrict__ sb,    // [4]
    const float* __restrict__ fa,    // [2048][5]
    const float* __restrict__ a_sc,  // [1]
    const float* __restrict__ fb,    // [2048]
    const float* __restrict__ b_sc,  // [1]
    const float* __restrict__ w,     // [2048]
    float* __restrict__ out)
{
    const int tid = threadIdx.x;              // 0..255
    const size_t base = (size_t)blockIdx.x * D;
    const int d0 = tid * 8;

    // ---- vectorized loads: h row (kept in regs), rms weight, projection tables
    float4 ha = *reinterpret_cast<const float4*>(h + base + d0);
    float4 hb = *reinterpret_cast<const float4*>(h + base + d0 + 4);
    float4 wa = *reinterpret_cast<const float4*>(w + d0);
    float4 wb = *reinterpret_cast<const float4*>(w + d0 + 4);
    float hv[8] = {ha.x, ha.y, ha.z, ha.w, hb.x, hb.y, hb.z, hb.w};
    float wv[8] = {wa.x, wa.y, wa.z, wa.w, wb.x, wb.y, wb.z, wb.w};

    // fa rows for d0..d0+7: 40 consecutive floats at fa + d0*5 (16B aligned)
    float fav[40];
    #pragma unroll
    for (int q = 0; q < 10; ++q) {
        float4 t = *reinterpret_cast<const float4*>(fa + (size_t)d0 * 5 + q * 4);
        fav[q*4+0] = t.x; fav[q*4+1] = t.y; fav[q*4+2] = t.z; fav[q*4+3] = t.w;
    }
    float4 fba = *reinterpret_cast<const float4*>(fb + d0);
    float4 fbb = *reinterpret_cast<const float4*>(fb + d0 + 4);
    float fbv[8] = {fba.x, fba.y, fba.z, fba.w, fbb.x, fbb.y, fbb.z, fbb.w};

    // ---- partial sums: [sumsq, dotA1..dotA4, dotB]
    float acc[6] = {0.f, 0.f, 0.f, 0.f, 0.f, 0.f};
    #pragma unroll
    for (int j = 0; j < 8; ++j) {
        const float x  = hv[j];
        const float xw = x * wv[j];
        acc[0] = fmaf(x,  x,            acc[0]);
        acc[1] = fmaf(xw, fav[j*5 + 1], acc[1]);
        acc[2] = fmaf(xw, fav[j*5 + 2], acc[2]);
        acc[3] = fmaf(xw, fav[j*5 + 3], acc[3]);
        acc[4] = fmaf(xw, fav[j*5 + 4], acc[4]);
        acc[5] = fmaf(xw, fbv[j],       acc[5]);
    }

    // ---- wave64 reduce, then 4-wave LDS combine
    #pragma unroll
    for (int off = 32; off > 0; off >>= 1) {
        #pragma unroll
        for (int k = 0; k < 6; ++k) acc[k] += __shfl_down(acc[k], off);
    }
    __shared__ float red[4][6];
    const int wave = tid >> 6;
    if ((tid & 63) == 0) {
        #pragma unroll
        for (int k = 0; k < 6; ++k) red[wave][k] = acc[k];
    }
    __syncthreads();
    float tot[6];
    #pragma unroll
    for (int k = 0; k < 6; ++k)
        tot[k] = red[0][k] + red[1][k] + red[2][k] + red[3][k];

    // ---- per-token scalars (uniform across block; sa/sb are scalar loads)
    const float rms = rsqrtf(tot[0] * (1.0f / (float)D) + EPS);
    const float a_scale = a_sc[0], b_scale = b_sc[0];

    float cs = 0.f;
    #pragma unroll
    for (int r = 0; r < RATE; ++r)
        #pragma unroll
        for (int c = 1; c <= RATE; ++c)
            cs += sa[r * (RATE + 1) + c];
    const float sbsum = sb[0] + sb[1] + sb[2] + sb[3];

    const float s_h  = (float)RATE * a_scale *
        (tanhf(tot[1] * rms) + tanhf(tot[2] * rms) +
         tanhf(tot[3] * rms) + tanhf(tot[4] * rms)) + cs;
    const float s_ho = (float)RATE * b_scale * tanhf(tot[5] * rms) + sbsum;

    // ---- fused epilogue: out = s_ho*h_o + s_h*h  (h already in regs)
    float4 oa = *reinterpret_cast<const float4*>(h_o + base + d0);
    float4 ob = *reinterpret_cast<const float4*>(h_o + base + d0 + 4);
    float4 r0, r1;
    r0.x = fmaf(s_ho, oa.x, s_h * hv[0]);
    r0.y = fmaf(s_ho, oa.y, s_h * hv[1]);
    r0.z = fmaf(s_ho, oa.z, s_h * hv[2]);
    r0.w = fmaf(s_ho, oa.w, s_h * hv[3]);
    r1.x = fmaf(s_ho, ob.x, s_h * hv[4]);
    r1.y = fmaf(s_ho, ob.y, s_h * hv[5]);
    r1.z = fmaf(s_ho, ob.z, s_h * hv[6]);
    r1.w = fmaf(s_ho, ob.w, s_h * hv[7]);
    *reinterpret_cast<float4*>(out + base + d0)     = r0;
    *reinterpret_cast<float4*>(out + base + d0 + 4) = r1;
}

extern "C" void kernel_launch(void* const* d_in, const int* in_sizes, int n_in,
                              void* d_out, int out_size, void* d_ws, size_t ws_size,
                              hipStream_t stream) {
    const float* h    = (const float*)d_in[0];
    const float* h_o  = (const float*)d_in[1];
    const float* sa   = (const float*)d_in[2];
    const float* sb   = (const float*)d_in[3];
    const float* fa   = (const float*)d_in[4];
    const float* a_sc = (const float*)d_in[5];
    const float* fb   = (const float*)d_in[6];
    const float* b_sc = (const float*)d_in[7];
    const float* w    = (const float*)d_in[8];
    float* out = (float*)d_out;

    const int ntok = in_sizes[0] / D;  // B*L = 16384
    hyperconn_kernel<<<ntok, 256, 0, stream>>>(h, h_o, sa, sb, fa, a_sc, fb, b_sc, w, out);
}

// Round 2
// 84.194 us; speedup vs baseline: 1.3706x; 1.3706x over previous
//
#include <hip/hip_runtime.h>
#include <math.h>

// out[d] = s_ho * h_o[d] + s_h * h[d], per token scalars from 6 reductions.
// One 256-thread block handles TPB=8 consecutive tokens, software-pipelined:
// token t+1's h/h_o loads are in flight while token t is reduced, so HBM
// latency hides under the shuffle/LDS/tanh chain. Tables hoisted per block.

constexpr int D    = 2048;
constexpr int RATE = 4;
constexpr float EPS = 1e-5f;
constexpr int TPB  = 8;   // tokens per block (16384 % 8 == 0)

__global__ __launch_bounds__(256) void hyperconn_kernel(
    const float* __restrict__ h,
    const float* __restrict__ h_o,
    const float* __restrict__ sa,    // [4][5]
    const float* __restrict__ sb,    // [4]
    const float* __restrict__ fa,    // [2048][5]
    const float* __restrict__ a_sc,  // [1]
    const float* __restrict__ fb,    // [2048]
    const float* __restrict__ b_sc,  // [1]
    const float* __restrict__ w,     // [2048]
    float* __restrict__ out)
{
    const int tid  = threadIdx.x;          // 0..255
    const int d0   = tid * 8;
    const int wave = tid >> 6;

    // ---- per-block constant tables (hoisted out of the token loop)
    float4 wa = *reinterpret_cast<const float4*>(w + d0);
    float4 wb = *reinterpret_cast<const float4*>(w + d0 + 4);
    const float wv[8] = {wa.x, wa.y, wa.z, wa.w, wb.x, wb.y, wb.z, wb.w};

    float fav[32];  // fa[d0+j][c], c=1..4 (col 0 unused)
    {
        float tmp[40];
        #pragma unroll
        for (int q = 0; q < 10; ++q) {
            float4 t = *reinterpret_cast<const float4*>(fa + (size_t)d0 * 5 + q * 4);
            tmp[q*4+0]=t.x; tmp[q*4+1]=t.y; tmp[q*4+2]=t.z; tmp[q*4+3]=t.w;
        }
        #pragma unroll
        for (int j = 0; j < 8; ++j)
            #pragma unroll
            for (int c = 0; c < 4; ++c)
                fav[j*4+c] = tmp[j*5 + 1 + c];
    }
    float4 fba = *reinterpret_cast<const float4*>(fb + d0);
    float4 fbb = *reinterpret_cast<const float4*>(fb + d0 + 4);
    const float fbv[8] = {fba.x, fba.y, fba.z, fba.w, fbb.x, fbb.y, fbb.z, fbb.w};

    const float a4 = a_sc[0] * (float)RATE;
    const float b4 = b_sc[0] * (float)RATE;
    float cs = 0.f;
    #pragma unroll
    for (int r = 0; r < RATE; ++r)
        #pragma unroll
        for (int c = 1; c <= RATE; ++c)
            cs += sa[r * (RATE + 1) + c];
    const float sbsum = sb[0] + sb[1] + sb[2] + sb[3];

    __shared__ float red[2][4][6];   // parity-buffered: 1 barrier per token

    const size_t t0 = (size_t)blockIdx.x * TPB;

    // ---- prologue: token 0 loads into buffer 0
    float4 hb0[2], hb1[2], ob0[2], ob1[2];
    {
        const size_t base = t0 * D + d0;
        hb0[0] = *reinterpret_cast<const float4*>(h   + base);
        hb1[0] = *reinterpret_cast<const float4*>(h   + base + 4);
        ob0[0] = *reinterpret_cast<const float4*>(h_o + base);
        ob1[0] = *reinterpret_cast<const float4*>(h_o + base + 4);
    }

    #pragma unroll
    for (int i = 0; i < TPB; ++i) {
        const int cur = i & 1;
        const int nxt = cur ^ 1;

        // ---- prefetch token i+1 (compile-time guard after full unroll)
        if (i + 1 < TPB) {
            const size_t nb = (t0 + i + 1) * D + d0;
            hb0[nxt] = *reinterpret_cast<const float4*>(h   + nb);
            hb1[nxt] = *reinterpret_cast<const float4*>(h   + nb + 4);
            ob0[nxt] = *reinterpret_cast<const float4*>(h_o + nb);
            ob1[nxt] = *reinterpret_cast<const float4*>(h_o + nb + 4);
        }

        const float hv[8] = {hb0[cur].x, hb0[cur].y, hb0[cur].z, hb0[cur].w,
                             hb1[cur].x, hb1[cur].y, hb1[cur].z, hb1[cur].w};

        // ---- partials: [sumsq, dotA1..dotA4, dotB]
        float acc[6] = {0.f, 0.f, 0.f, 0.f, 0.f, 0.f};
        #pragma unroll
        for (int j = 0; j < 8; ++j) {
            const float x  = hv[j];
            const float xw = x * wv[j];
            acc[0] = fmaf(x,  x,          acc[0]);
            acc[1] = fmaf(xw, fav[j*4+0], acc[1]);
            acc[2] = fmaf(xw, fav[j*4+1], acc[2]);
            acc[3] = fmaf(xw, fav[j*4+2], acc[3]);
            acc[4] = fmaf(xw, fav[j*4+3], acc[4]);
            acc[5] = fmaf(xw, fbv[j],     acc[5]);
        }

        // ---- wave64 shuffle reduce, then 4-wave LDS combine
        #pragma unroll
        for (int off = 32; off > 0; off >>= 1)
            #pragma unroll
            for (int k = 0; k < 6; ++k) acc[k] += __shfl_down(acc[k], off);

        if ((tid & 63) == 0) {
            #pragma unroll
            for (int k = 0; k < 6; ++k) red[cur][wave][k] = acc[k];
        }
        __syncthreads();
        float tot[6];
        #pragma unroll
        for (int k = 0; k < 6; ++k)
            tot[k] = red[cur][0][k] + red[cur][1][k] + red[cur][2][k] + red[cur][3][k];

        // ---- per-token scalars
        const float rms  = rsqrtf(tot[0] * (1.0f / (float)D) + EPS);
        const float s_h  = a4 * (tanhf(tot[1] * rms) + tanhf(tot[2] * rms) +
                                 tanhf(tot[3] * rms) + tanhf(tot[4] * rms)) + cs;
        const float s_ho = b4 * tanhf(tot[5] * rms) + sbsum;

        // ---- epilogue: out = s_ho*h_o + s_h*h (both already in registers)
        const size_t base = (t0 + i) * D + d0;
        float4 r0, r1;
        r0.x = fmaf(s_ho, ob0[cur].x, s_h * hv[0]);
        r0.y = fmaf(s_ho, ob0[cur].y, s_h * hv[1]);
        r0.z = fmaf(s_ho, ob0[cur].z, s_h * hv[2]);
        r0.w = fmaf(s_ho, ob0[cur].w, s_h * hv[3]);
        r1.x = fmaf(s_ho, ob1[cur].x, s_h * hv[4]);
        r1.y = fmaf(s_ho, ob1[cur].y, s_h * hv[5]);
        r1.z = fmaf(s_ho, ob1[cur].z, s_h * hv[6]);
        r1.w = fmaf(s_ho, ob1[cur].w, s_h * hv[7]);
        *reinterpret_cast<float4*>(out + base)     = r0;
        *reinterpret_cast<float4*>(out + base + 4) = r1;
    }
}

extern "C" void kernel_launch(void* const* d_in, const int* in_sizes, int n_in,
                              void* d_out, int out_size, void* d_ws, size_t ws_size,
                              hipStream_t stream) {
    const float* h    = (const float*)d_in[0];
    const float* h_o  = (const float*)d_in[1];
    const float* sa   = (const float*)d_in[2];
    const float* sb   = (const float*)d_in[3];
    const float* fa   = (const float*)d_in[4];
    const float* a_sc = (const float*)d_in[5];
    const float* fb   = (const float*)d_in[6];
    const float* b_sc = (const float*)d_in[7];
    const float* w    = (const float*)d_in[8];
    float* out = (float*)d_out;

    const int ntok   = in_sizes[0] / D;       // B*L = 16384
    const int blocks = ntok / TPB;            // 2048
    hyperconn_kernel<<<blocks, 256, 0, stream>>>(h, h_o, sa, sb, fa, a_sc, fb, b_sc, w, out);
}